// Round 1
// 324.206 us; speedup vs baseline: 1.0873x; 1.0873x over previous
//
#include <hip/hip_runtime.h>
#include <math.h>

// Problem constants (from reference)
constexpr int B_SZ = 16384;
constexpr long long CELLS = 4194304;   // 16384*256 cells, 2 anchor slots each
constexpr int CLS_CELLS = 8192;        // logits[:batch_size] -> first 8192 cells get cls loss
constexpr float NOOBJ_SCALE = 0.5f;
constexpr float COORD_SCALE = 5.0f;

constexpr int TPB = 256;               // threads per block == cells per block
constexpr int PRED_PITCH = 13;         // 12 floats + 1 pad (odd stride -> 2-way LDS = free)
constexpr int TGT_PITCH  = 9;          // 8 floats + 1 pad
constexpr int NBLOCKS = (int)(CELLS / TPB);   // 16384 partial slots in d_ws (128 KB)

// Native clang vector so __builtin_nontemporal_load is applicable (float4 is a struct).
typedef float f4 __attribute__((ext_vector_type(4)));

// Per-(cell,slot) loss contribution.
// pred slot layout: offset=p0, dur=p1, conf=p2, cls=p3..p5  (slot1: +6)
// target slot layout: conf, cls, offset, dur                (slot1: +4)
__device__ __forceinline__ float slot_loss(float pc, float l0, float l1, float l2,
                                           float po, float pd,
                                           float tc, float tcls, float to, float td,
                                           bool do_cls) {
    float d = tc - pc;
    bool obj = (tc == 1.0f);
    float w = obj ? 1.0f : ((tc == 0.0f) ? NOOBJ_SCALE : 0.0f);
    float r = w * d * d;

    if (obj) {
        float doff = to - po;
        r += COORD_SCALE * doff * doff;
        float dd = sqrtf(td) - sqrtf(pd);
        r += COORD_SCALE * dd * dd;
    }
    if (do_cls) {
        float x0, x1, x2;
        int idx;
        if (obj) { x0 = l0; x1 = l1; x2 = l2; idx = (int)tcls; }
        else     { x0 = 0.f; x1 = 0.f; x2 = 0.f; idx = 0; }
        float m = fmaxf(x0, fmaxf(x1, x2));
        float lse = logf(expf(x0 - m) + expf(x1 - m) + expf(x2 - m)) + m;
        float li = (idx == 0) ? x0 : ((idx == 1) ? x1 : x2);
        r += lse - li;   // cross-entropy = logsumexp - logit[target]
    }
    return r;
}

__global__ __launch_bounds__(256) void ensemble_loss_kernel(
        const float* __restrict__ pred,
        const float* __restrict__ target,
        double* __restrict__ partials) {
    // Padded LDS tiles: 256*13*4 = 13312 B + 256*9*4 = 9216 B = ~22.5 KB
    __shared__ float spred[TPB * PRED_PITCH];
    __shared__ float star[TPB * TGT_PITCH];
    __shared__ float wsum[4];

    const int tid = threadIdx.x;
    const long long cell0 = (long long)blockIdx.x * TPB;

    // ---- stage pred: 768 float4/block, lane-contiguous (coalesced) ----
    // float4 #g covers words 4g..4g+3; 3 float4 per cell, never straddles.
    // Streaming single-use data: nontemporal (no reuse; poison fill evicts caches anyway).
    const f4* __restrict__ pbase = (const f4*)pred + cell0 * 3;
    #pragma unroll
    for (int r = 0; r < 3; ++r) {
        int g = r * TPB + tid;              // 0..767
        f4 v = __builtin_nontemporal_load(pbase + g);
        int cell = g / 3;                   // magic-mul div
        int sub  = g - cell * 3;
        int a = cell * PRED_PITCH + 4 * sub;
        spred[a + 0] = v.x; spred[a + 1] = v.y;
        spred[a + 2] = v.z; spred[a + 3] = v.w;
    }
    // ---- stage target: 512 float4/block, lane-contiguous ----
    const f4* __restrict__ tbase = (const f4*)target + cell0 * 2;
    #pragma unroll
    for (int r = 0; r < 2; ++r) {
        int g = r * TPB + tid;              // 0..511
        f4 v = __builtin_nontemporal_load(tbase + g);
        int cell = g >> 1;
        int sub  = g & 1;
        int a = cell * TGT_PITCH + 4 * sub;
        star[a + 0] = v.x; star[a + 1] = v.y;
        star[a + 2] = v.z; star[a + 3] = v.w;
    }
    __syncthreads();

    // ---- compute: thread t handles cell (cell0 + t); padded stride reads
    //      are 2 lanes/bank (free) ----
    const float* P = &spred[tid * PRED_PITCH];
    const float* T = &star[tid * TGT_PITCH];
    const bool do_cls = (cell0 + tid) < CLS_CELLS;   // blocks 0..31 only (wave-uniform)

    float acc = 0.0f;
    acc += slot_loss(P[2], P[3], P[4], P[5], P[0], P[1],
                     T[0], T[1], T[2], T[3], do_cls);
    acc += slot_loss(P[8], P[9], P[10], P[11], P[6], P[7],
                     T[4], T[5], T[6], T[7], do_cls);

    // wave(64) shuffle reduction
    for (int off = 32; off > 0; off >>= 1)
        acc += __shfl_down(acc, off, 64);

    int lane = tid & 63;
    int wv = tid >> 6;
    if (lane == 0) wsum[wv] = acc;
    __syncthreads();
    if (tid == 0) {
        float s = wsum[0] + wsum[1] + wsum[2] + wsum[3];
        // Private slot per block: written unconditionally every launch, so the
        // 0xAA workspace poison needs NO memset and there are NO atomics.
        partials[blockIdx.x] = (double)s;
    }
}

__global__ __launch_bounds__(256) void finalize_kernel(
        const double* __restrict__ partials,
        float* __restrict__ out) {
    __shared__ double wsum[4];
    const int tid = threadIdx.x;

    // 16384 doubles = 128 KB; thread t reads slots t, t+256, ... (coalesced).
    double s = 0.0;
    #pragma unroll
    for (int i = 0; i < NBLOCKS / TPB; ++i)
        s += partials[i * TPB + tid];

    for (int off = 32; off > 0; off >>= 1)
        s += __shfl_down(s, off, 64);

    int lane = tid & 63;
    int wv = tid >> 6;
    if (lane == 0) wsum[wv] = s;
    __syncthreads();
    if (tid == 0) {
        double t = wsum[0] + wsum[1] + wsum[2] + wsum[3];
        out[0] = (float)(t * (1.0 / (double)B_SZ));
    }
}

extern "C" void kernel_launch(void* const* d_in, const int* in_sizes, int n_in,
                              void* d_out, int out_size, void* d_ws, size_t ws_size,
                              hipStream_t stream) {
    const float* pred   = (const float*)d_in[0];
    const float* target = (const float*)d_in[1];
    float* out = (float*)d_out;
    double* partials = (double*)d_ws;

    // No memset: every one of the 16384 partial slots is written unconditionally,
    // so the per-launch 0xAA poison of d_ws is harmless. 2 dispatches total.
    ensemble_loss_kernel<<<NBLOCKS, TPB, 0, stream>>>(pred, target, partials);
    finalize_kernel<<<1, TPB, 0, stream>>>(partials, out);
}